// Round 1
// baseline (1889.053 us; speedup 1.0000x reference)
//
#include <hip/hip_runtime.h>

#define N_NODES 100000
#define N_EDGES 1600000
// IN_DIM=512, HID_DIM=128, OUT_DIM=64

// ---------------------------------------------------------------------------
// Tiled fp32 GEMM: C[N,M] = op(A)[N,K] @ W[K,M], op = relu if RELU_IN.
// Block: 256 threads, 64-row x M-col output tile. KC=16 k-chunks staged in LDS.
// ---------------------------------------------------------------------------
template<int K, int M, bool RELU_IN>
__global__ __launch_bounds__(256) void gemm_kernel(const float* __restrict__ A,
                                                   const float* __restrict__ W,
                                                   float* __restrict__ C, int N) {
    constexpr int BM  = 64;        // rows per block
    constexpr int KC  = 16;        // k-chunk
    constexpr int CPT = 4;         // cols per thread
    constexpr int CG  = M / CPT;   // col groups (32 for M=128, 16 for M=64)
    constexpr int RG  = 256 / CG;  // row groups (8 / 16)
    constexpr int RPT = BM / RG;   // rows per thread (8 / 4)

    __shared__ float As[BM][KC];
    __shared__ float Ws[KC][M];

    const int tid       = threadIdx.x;
    const int block_row = blockIdx.x * BM;
    const int cg = tid % CG, rg = tid / CG;
    const int c0 = cg * CPT, r0 = rg * RPT;

    float acc[RPT][CPT];
#pragma unroll
    for (int r = 0; r < RPT; ++r)
#pragma unroll
        for (int c = 0; c < CPT; ++c) acc[r][c] = 0.f;

    for (int k0 = 0; k0 < K; k0 += KC) {
        // A tile: 64x16 = 1024 floats, one float4 per thread (along K, contiguous)
        {
            const int idx  = tid * 4;
            const int ar   = idx / KC;
            const int ak   = idx % KC;     // multiple of 4
            const int grow = block_row + ar;
            float4 v = make_float4(0.f, 0.f, 0.f, 0.f);
            if (grow < N)
                v = *reinterpret_cast<const float4*>(A + (size_t)grow * K + k0 + ak);
            if (RELU_IN) {
                v.x = fmaxf(v.x, 0.f); v.y = fmaxf(v.y, 0.f);
                v.z = fmaxf(v.z, 0.f); v.w = fmaxf(v.w, 0.f);
            }
            *reinterpret_cast<float4*>(&As[ar][ak]) = v;
        }
        // W tile: KC x M floats (2048 for M=128 -> 2 float4/thread; 1024 for M=64 -> 1)
#pragma unroll
        for (int i = 0; i < (KC * M) / 1024; ++i) {
            const int idx = (tid + i * 256) * 4;
            const int wk  = idx / M;
            const int wc  = idx % M;
            *reinterpret_cast<float4*>(&Ws[wk][wc]) =
                *reinterpret_cast<const float4*>(W + (size_t)(k0 + wk) * M + wc);
        }
        __syncthreads();

#pragma unroll
        for (int k = 0; k < KC; ++k) {
            float wv[CPT];
#pragma unroll
            for (int c = 0; c < CPT; ++c) wv[c] = Ws[k][c0 + c];
#pragma unroll
            for (int r = 0; r < RPT; ++r) {
                const float av = As[r0 + r][k];
#pragma unroll
                for (int c = 0; c < CPT; ++c) acc[r][c] = fmaf(av, wv[c], acc[r][c]);
            }
        }
        __syncthreads();
    }

#pragma unroll
    for (int r = 0; r < RPT; ++r) {
        const int grow = block_row + r0 + r;
        if (grow < N)
            *reinterpret_cast<float4*>(C + (size_t)grow * M + c0) =
                make_float4(acc[r][0], acc[r][1], acc[r][2], acc[r][3]);
    }
}

// ---------------------------------------------------------------------------
// buf[i][d] = bias[d] for all i  (initializes aggregation target with bias)
// ---------------------------------------------------------------------------
template<int DIM>
__global__ __launch_bounds__(256) void init_bias_kernel(float* __restrict__ buf,
                                                        const float* __restrict__ b) {
    const int i = blockIdx.x * 256 + threadIdx.x;
    if (i < N_NODES * DIM) buf[i] = b[i & (DIM - 1)];
}

// ---------------------------------------------------------------------------
// Edge aggregation, 128 dims: wave per edge, float2 per lane.
// agg[rows[e]][:] += vals[e] * sup[cols[e]][:]
// ---------------------------------------------------------------------------
__global__ __launch_bounds__(256) void edge_agg128_kernel(const int* __restrict__ rows,
                                                          const int* __restrict__ cols,
                                                          const float* __restrict__ vals,
                                                          const float* __restrict__ sup,
                                                          float* __restrict__ agg) {
    const int wid  = (blockIdx.x * 256 + threadIdx.x) >> 6;  // edge id
    const int lane = threadIdx.x & 63;
    if (wid >= N_EDGES) return;
    const int   r = rows[wid];
    const int   c = cols[wid];
    const float v = vals[wid];
    const float2 s = *reinterpret_cast<const float2*>(sup + (size_t)c * 128 + lane * 2);
    float* dst = agg + (size_t)r * 128 + lane * 2;
    atomicAdd(dst,     v * s.x);
    atomicAdd(dst + 1, v * s.y);
}

// Edge aggregation, 64 dims: wave per edge, one float per lane.
__global__ __launch_bounds__(256) void edge_agg64_kernel(const int* __restrict__ rows,
                                                         const int* __restrict__ cols,
                                                         const float* __restrict__ vals,
                                                         const float* __restrict__ sup,
                                                         float* __restrict__ agg) {
    const int wid  = (blockIdx.x * 256 + threadIdx.x) >> 6;
    const int lane = threadIdx.x & 63;
    if (wid >= N_EDGES) return;
    const int   r = rows[wid];
    const int   c = cols[wid];
    const float v = vals[wid];
    const float s = sup[(size_t)c * 64 + lane];
    atomicAdd(agg + (size_t)r * 64 + lane, v * s);
}

// ---------------------------------------------------------------------------
extern "C" void kernel_launch(void* const* d_in, const int* in_sizes, int n_in,
                              void* d_out, int out_size, void* d_ws, size_t ws_size,
                              hipStream_t stream) {
    const float* x    = (const float*)d_in[0];
    const int*   rows = (const int*)d_in[1];
    const int*   cols = (const int*)d_in[2];
    const float* vals = (const float*)d_in[3];
    const float* W0   = (const float*)d_in[4];
    const float* b0   = (const float*)d_in[5];
    const float* W1   = (const float*)d_in[6];
    const float* b1   = (const float*)d_in[7];
    float*       out  = (float*)d_out;

    // Workspace layout (fp32): sup0[N,128] | h[N,128] | sup1[N,64]  = 128 MB
    float* sup0 = (float*)d_ws;
    float* h    = sup0 + (size_t)N_NODES * 128;
    float* sup1 = h    + (size_t)N_NODES * 128;

    const int gemm_blocks = (N_NODES + 63) / 64;

    // Layer 0: sup0 = x @ W0
    gemm_kernel<512, 128, false><<<gemm_blocks, 256, 0, stream>>>(x, W0, sup0, N_NODES);
    // h = b0 (broadcast); h += scatter-add of vals * sup0[cols]
    init_bias_kernel<128><<<(N_NODES * 128 + 255) / 256, 256, 0, stream>>>(h, b0);
    edge_agg128_kernel<<<N_EDGES / 4, 256, 0, stream>>>(rows, cols, vals, sup0, h);

    // Layer 1: sup1 = relu(h) @ W1   (h already includes b0)
    gemm_kernel<128, 64, true><<<gemm_blocks, 256, 0, stream>>>(h, W1, sup1, N_NODES);
    // out = b1 (broadcast); out += scatter-add of vals * sup1[cols]
    init_bias_kernel<64><<<(N_NODES * 64 + 255) / 256, 256, 0, stream>>>(out, b1);
    edge_agg64_kernel<<<N_EDGES / 4, 256, 0, stream>>>(rows, cols, vals, sup1, out);
}

// Round 2
// 636.057 us; speedup vs baseline: 2.9699x; 2.9699x over previous
//
#include <hip/hip_runtime.h>

#define N_NODES 100000
#define N_EDGES 1600000
// IN_DIM=512, HID_DIM=128, OUT_DIM=64

// ---------------------------------------------------------------------------
// Tiled fp32 GEMM: C[N,M] = op(A)[N,K] @ W[K,M], op = relu if RELU_IN.
// ---------------------------------------------------------------------------
template<int K, int M, bool RELU_IN>
__global__ __launch_bounds__(256) void gemm_kernel(const float* __restrict__ A,
                                                   const float* __restrict__ W,
                                                   float* __restrict__ C, int N) {
    constexpr int BM  = 64;
    constexpr int KC  = 16;
    constexpr int CPT = 4;
    constexpr int CG  = M / CPT;
    constexpr int RG  = 256 / CG;
    constexpr int RPT = BM / RG;

    __shared__ float As[BM][KC];
    __shared__ float Ws[KC][M];

    const int tid       = threadIdx.x;
    const int block_row = blockIdx.x * BM;
    const int cg = tid % CG, rg = tid / CG;
    const int c0 = cg * CPT, r0 = rg * RPT;

    float acc[RPT][CPT];
#pragma unroll
    for (int r = 0; r < RPT; ++r)
#pragma unroll
        for (int c = 0; c < CPT; ++c) acc[r][c] = 0.f;

    for (int k0 = 0; k0 < K; k0 += KC) {
        {
            const int idx  = tid * 4;
            const int ar   = idx / KC;
            const int ak   = idx % KC;
            const int grow = block_row + ar;
            float4 v = make_float4(0.f, 0.f, 0.f, 0.f);
            if (grow < N)
                v = *reinterpret_cast<const float4*>(A + (size_t)grow * K + k0 + ak);
            if (RELU_IN) {
                v.x = fmaxf(v.x, 0.f); v.y = fmaxf(v.y, 0.f);
                v.z = fmaxf(v.z, 0.f); v.w = fmaxf(v.w, 0.f);
            }
            *reinterpret_cast<float4*>(&As[ar][ak]) = v;
        }
#pragma unroll
        for (int i = 0; i < (KC * M) / 1024; ++i) {
            const int idx = (tid + i * 256) * 4;
            const int wk  = idx / M;
            const int wc  = idx % M;
            *reinterpret_cast<float4*>(&Ws[wk][wc]) =
                *reinterpret_cast<const float4*>(W + (size_t)(k0 + wk) * M + wc);
        }
        __syncthreads();

#pragma unroll
        for (int k = 0; k < KC; ++k) {
            float wv[CPT];
#pragma unroll
            for (int c = 0; c < CPT; ++c) wv[c] = Ws[k][c0 + c];
#pragma unroll
            for (int r = 0; r < RPT; ++r) {
                const float av = As[r0 + r][k];
#pragma unroll
                for (int c = 0; c < CPT; ++c) acc[r][c] = fmaf(av, wv[c], acc[r][c]);
            }
        }
        __syncthreads();
    }

#pragma unroll
    for (int r = 0; r < RPT; ++r) {
        const int grow = block_row + r0 + r;
        if (grow < N)
            *reinterpret_cast<float4*>(C + (size_t)grow * M + c0) =
                make_float4(acc[r][0], acc[r][1], acc[r][2], acc[r][3]);
    }
}

// ---------------------------------------------------------------------------
// CSR construction: zero -> histogram -> 2-level exclusive scan -> scatter
// ---------------------------------------------------------------------------
__global__ __launch_bounds__(256) void zero_kernel(int* __restrict__ p, int n) {
    const int i = blockIdx.x * 256 + threadIdx.x;
    if (i < n) p[i] = 0;
}

__global__ __launch_bounds__(256) void hist_kernel(const int* __restrict__ rows,
                                                   int* __restrict__ deg) {
    const int e = blockIdx.x * 256 + threadIdx.x;
    atomicAdd(&deg[rows[e]], 1);
}

// Block partial sums: each block sums 1024 deg entries.
__global__ __launch_bounds__(256) void sum_blocks_kernel(const int* __restrict__ deg,
                                                         int* __restrict__ bsum) {
    __shared__ int red[256];
    const int tid = threadIdx.x;
    const int i4  = blockIdx.x * 1024 + tid * 4;
    int s = 0;
#pragma unroll
    for (int k = 0; k < 4; ++k) {
        const int i = i4 + k;
        if (i < N_NODES) s += deg[i];
    }
    red[tid] = s;
    __syncthreads();
#pragma unroll
    for (int off = 128; off > 0; off >>= 1) {
        if (tid < off) red[tid] += red[tid + off];
        __syncthreads();
    }
    if (tid == 0) bsum[blockIdx.x] = red[0];
}

// Single-block exclusive scan of block sums (nblk <= 256).
__global__ __launch_bounds__(256) void scan_bsum_kernel(const int* __restrict__ bsum,
                                                        int* __restrict__ boffs, int nblk) {
    __shared__ int sh[256];
    const int tid = threadIdx.x;
    sh[tid] = (tid < nblk) ? bsum[tid] : 0;
    __syncthreads();
    if (tid == 0) {
        int acc = 0;
        for (int b = 0; b < nblk; ++b) { const int t = sh[b]; sh[b] = acc; acc += t; }
    }
    __syncthreads();
    if (tid < nblk) boffs[tid] = sh[tid];
}

// Per-block exclusive scan + global offset -> row_ptr; also seed cursor.
__global__ __launch_bounds__(256) void scan_final_kernel(const int* __restrict__ deg,
                                                         const int* __restrict__ boffs,
                                                         int* __restrict__ row_ptr,
                                                         int* __restrict__ cursor) {
    __shared__ int tsum[256];
    const int tid    = threadIdx.x;
    const int base_i = blockIdx.x * 1024 + tid * 4;
    int d[4];
#pragma unroll
    for (int k = 0; k < 4; ++k) {
        const int i = base_i + k;
        d[k] = (i < N_NODES) ? deg[i] : 0;
    }
    const int s = d[0] + d[1] + d[2] + d[3];
    tsum[tid] = s;
    __syncthreads();
    // inclusive Hillis-Steele
    for (int off = 1; off < 256; off <<= 1) {
        const int t = (tid >= off) ? tsum[tid - off] : 0;
        __syncthreads();
        tsum[tid] += t;
        __syncthreads();
    }
    int p = tsum[tid] - s + boffs[blockIdx.x];  // exclusive prefix for element base_i
#pragma unroll
    for (int k = 0; k < 4; ++k) {
        const int i = base_i + k;
        if (i < N_NODES) {
            row_ptr[i] = p;
            cursor[i]  = p;
            if (i == N_NODES - 1) row_ptr[N_NODES] = p + d[k];
        }
        p += d[k];
    }
}

__global__ __launch_bounds__(256) void scatter_kernel(const int* __restrict__ rows,
                                                      const int* __restrict__ cols,
                                                      const float* __restrict__ vals,
                                                      int* __restrict__ cursor,
                                                      int* __restrict__ edge_col,
                                                      float* __restrict__ edge_val) {
    const int e = blockIdx.x * 256 + threadIdx.x;
    const int r = rows[e];
    const int pos = atomicAdd(&cursor[r], 1);
    edge_col[pos] = cols[e];
    edge_val[pos] = vals[e];
}

// ---------------------------------------------------------------------------
// Atomic-free SpMM: one wave per output row.
// agg[r][:] = bias[:] + sum_{j in row r} val_j * sup[col_j][:]
// ---------------------------------------------------------------------------
template<int DIM>  // 128 (float2/lane) or 64 (float/lane)
__global__ __launch_bounds__(256) void spmm_kernel(const int* __restrict__ row_ptr,
                                                   const int* __restrict__ edge_col,
                                                   const float* __restrict__ edge_val,
                                                   const float* __restrict__ sup,
                                                   const float* __restrict__ bias,
                                                   float* __restrict__ agg) {
    const int wid  = (blockIdx.x * 256 + threadIdx.x) >> 6;  // row id
    const int lane = threadIdx.x & 63;
    if (wid >= N_NODES) return;

    const int start = row_ptr[wid];
    const int end   = row_ptr[wid + 1];

    float ax = 0.f, ay = 0.f;

    for (int j0 = start; j0 < end; j0 += 64) {
        int   c = 0;
        float v = 0.f;
        const int j = j0 + lane;
        if (j < end) { c = edge_col[j]; v = edge_val[j]; }
        const int cnt = min(64, end - j0);
        for (int k = 0; k < cnt; ++k) {
            const int   bc = __shfl(c, k);
            const float bv = __shfl(v, k);
            if (DIM == 128) {
                const float2 s = *reinterpret_cast<const float2*>(sup + (size_t)bc * 128 + lane * 2);
                ax = fmaf(bv, s.x, ax);
                ay = fmaf(bv, s.y, ay);
            } else {
                ax = fmaf(bv, sup[(size_t)bc * 64 + lane], ax);
            }
        }
    }

    if (DIM == 128) {
        float* dst = agg + (size_t)wid * 128 + lane * 2;
        dst[0] = ax + bias[lane * 2];
        dst[1] = ay + bias[lane * 2 + 1];
    } else {
        agg[(size_t)wid * 64 + lane] = ax + bias[lane];
    }
}

// ---------------------------------------------------------------------------
extern "C" void kernel_launch(void* const* d_in, const int* in_sizes, int n_in,
                              void* d_out, int out_size, void* d_ws, size_t ws_size,
                              hipStream_t stream) {
    const float* x    = (const float*)d_in[0];
    const int*   rows = (const int*)d_in[1];
    const int*   cols = (const int*)d_in[2];
    const float* vals = (const float*)d_in[3];
    const float* W0   = (const float*)d_in[4];
    const float* b0   = (const float*)d_in[5];
    const float* W1   = (const float*)d_in[6];
    const float* b1   = (const float*)d_in[7];
    float*       out  = (float*)d_out;

    // Workspace carve (16B-aligned chunks)
    char* p = (char*)d_ws;
    float* sup0     = (float*)p;                 p += (size_t)N_NODES * 128 * 4;   // 51.2 MB (reused as sup1)
    float* h        = (float*)p;                 p += (size_t)N_NODES * 128 * 4;   // 51.2 MB
    int*   deg      = (int*)p;                   p += (size_t)N_NODES * 4;
    int*   row_ptr  = (int*)p;                   p += (size_t)(N_NODES + 4) * 4;
    int*   cursor   = (int*)p;                   p += (size_t)N_NODES * 4;
    int*   bsum     = (int*)p;                   p += 256 * 4;
    int*   boffs    = (int*)p;                   p += 256 * 4;
    int*   edge_col = (int*)p;                   p += (size_t)N_EDGES * 4;
    float* edge_val = (float*)p;                 p += (size_t)N_EDGES * 4;
    float* sup1     = sup0;  // layer-0 support dead once h is built

    constexpr int SCAN_BLOCKS = (N_NODES + 1023) / 1024;  // 98
    const int edge_blocks = N_EDGES / 256;                // 6250
    const int node_blocks = (N_NODES + 255) / 256;        // 391
    const int gemm_blocks = (N_NODES + 63) / 64;
    const int spmm_blocks = (N_NODES * 64 + 255) / 256;   // 25000

    // ---- CSR build (shared by both layers) ----
    zero_kernel<<<node_blocks, 256, 0, stream>>>(deg, N_NODES);
    hist_kernel<<<edge_blocks, 256, 0, stream>>>(rows, deg);
    sum_blocks_kernel<<<SCAN_BLOCKS, 256, 0, stream>>>(deg, bsum);
    scan_bsum_kernel<<<1, 256, 0, stream>>>(bsum, boffs, SCAN_BLOCKS);
    scan_final_kernel<<<SCAN_BLOCKS, 256, 0, stream>>>(deg, boffs, row_ptr, cursor);
    scatter_kernel<<<edge_blocks, 256, 0, stream>>>(rows, cols, vals, cursor, edge_col, edge_val);

    // ---- Layer 0 ----
    gemm_kernel<512, 128, false><<<gemm_blocks, 256, 0, stream>>>(x, W0, sup0, N_NODES);
    spmm_kernel<128><<<spmm_blocks, 256, 0, stream>>>(row_ptr, edge_col, edge_val, sup0, b0, h);

    // ---- Layer 1 ----
    gemm_kernel<128, 64, true><<<gemm_blocks, 256, 0, stream>>>(h, W1, sup1, N_NODES);
    spmm_kernel<64><<<spmm_blocks, 256, 0, stream>>>(row_ptr, edge_col, edge_val, sup1, b1, out);
}

// Round 3
// 507.133 us; speedup vs baseline: 3.7250x; 1.2542x over previous
//
#include <hip/hip_runtime.h>

#define N_NODES 100000
#define N_EDGES 1600000
// IN_DIM=512, HID_DIM=128, OUT_DIM=64

typedef __attribute__((ext_vector_type(8))) short bf16x8;
typedef __attribute__((ext_vector_type(4))) float f32x4;

__device__ __forceinline__ unsigned short f2bf(float f) {
    unsigned int u = __builtin_bit_cast(unsigned int, f);
    u = (u + 0x7FFFu + ((u >> 16) & 1u)) >> 16;   // RNE
    return (unsigned short)u;
}
__device__ __forceinline__ float bfbits2f(unsigned int hi16) {
    return __builtin_bit_cast(float, hi16);        // hi16 already in top half
}

// ---------------------------------------------------------------------------
// W[K][M] fp32 (row-major) -> Wt[M][K] bf16 (transposed)
// ---------------------------------------------------------------------------
template<int K, int M>
__global__ __launch_bounds__(256) void convert_w_kernel(const float* __restrict__ W,
                                                        unsigned short* __restrict__ Wt) {
    const int i = blockIdx.x * 256 + threadIdx.x;
    if (i < K * M) {
        const int k = i / M, c = i % M;
        Wt[c * K + k] = f2bf(W[i]);
    }
}

// ---------------------------------------------------------------------------
// MFMA GEMM: C_bf16[N,M] = op(A_f32)[N,K] @ W[K,M], W given as Wt[M][K] bf16.
// Block: 256 thr = 4 waves (2x2), tile 128 x M. BK=32, one 16x16x32 MFMA per
// fragment per k-step. A converted fp32->bf16 during LDS staging.
// LDS row stride 56 ushorts (112 B): 16B-aligned, 28-bank step -> 2-way (free).
// ---------------------------------------------------------------------------
template<int K, int M, bool RELU>
__global__ __launch_bounds__(256) void mfma_gemm_kernel(const float* __restrict__ A,
                                                        const unsigned short* __restrict__ Wt,
                                                        unsigned short* __restrict__ C, int N) {
    constexpr int NF  = M / 32;   // n-fragments per wave (4 for M=128, 2 for M=64)
    constexpr int BNW = M / 2;    // wave n-width (64 / 32)
    constexpr int LDT = 56;       // LDS row stride in ushorts

    __shared__ __align__(16) unsigned short As[128 * LDT];
    __shared__ __align__(16) unsigned short Bs[M * LDT];

    const int tid  = threadIdx.x;
    const int lane = tid & 63;
    const int wid  = tid >> 6;
    const int wm   = wid >> 1;
    const int wn   = wid & 1;
    const int brow = blockIdx.x * 128;

    f32x4 acc[4][NF];
#pragma unroll
    for (int m = 0; m < 4; ++m)
#pragma unroll
        for (int n = 0; n < NF; ++n) acc[m][n] = (f32x4){0.f, 0.f, 0.f, 0.f};

    const unsigned short* aBase = As + (wm * 64 + (lane & 15)) * LDT + (lane >> 4) * 8;
    const unsigned short* bBase = Bs + (wn * BNW + (lane & 15)) * LDT + (lane >> 4) * 8;

    for (int k0 = 0; k0 < K; k0 += 32) {
        // ---- stage A: 128x32 fp32 -> bf16 (4 float4 per thread) ----
#pragma unroll
        for (int i = 0; i < 4; ++i) {
            const int f   = tid + i * 256;
            const int row = f >> 3;
            const int kq  = f & 7;
            const int gr  = brow + row;
            float4 v = {0.f, 0.f, 0.f, 0.f};
            if (gr < N) v = *reinterpret_cast<const float4*>(A + (size_t)gr * K + k0 + kq * 4);
            if (RELU) {
                v.x = fmaxf(v.x, 0.f); v.y = fmaxf(v.y, 0.f);
                v.z = fmaxf(v.z, 0.f); v.w = fmaxf(v.w, 0.f);
            }
            uint2 pk;
            pk.x = (unsigned int)f2bf(v.x) | ((unsigned int)f2bf(v.y) << 16);
            pk.y = (unsigned int)f2bf(v.z) | ((unsigned int)f2bf(v.w) << 16);
            *reinterpret_cast<uint2*>(As + row * LDT + kq * 4) = pk;
        }
        // ---- stage B: M x 32 bf16 copy (16B chunks) ----
#pragma unroll
        for (int i = 0; i < M / 64; ++i) {
            const int id = tid + i * 256;
            const int c  = id >> 2;
            const int kq = id & 3;
            const uint4 w = *reinterpret_cast<const uint4*>(Wt + (size_t)c * K + k0 + kq * 8);
            *reinterpret_cast<uint4*>(Bs + c * LDT + kq * 8) = w;
        }
        __syncthreads();

        bf16x8 af[4], bfr[NF];
#pragma unroll
        for (int m = 0; m < 4; ++m)
            af[m] = *reinterpret_cast<const bf16x8*>(aBase + m * 16 * LDT);
#pragma unroll
        for (int n = 0; n < NF; ++n)
            bfr[n] = *reinterpret_cast<const bf16x8*>(bBase + n * 16 * LDT);
#pragma unroll
        for (int m = 0; m < 4; ++m)
#pragma unroll
            for (int n = 0; n < NF; ++n)
                acc[m][n] = __builtin_amdgcn_mfma_f32_16x16x32_bf16(af[m], bfr[n], acc[m][n], 0, 0, 0);
        __syncthreads();
    }

    // ---- epilogue: C/D layout col=lane&15, row=(lane>>4)*4+j ----
    const int rbase = brow + wm * 64 + (lane >> 4) * 4;
    const int cbase = wn * BNW + (lane & 15);
#pragma unroll
    for (int m = 0; m < 4; ++m)
#pragma unroll
        for (int n = 0; n < NF; ++n)
#pragma unroll
            for (int j = 0; j < 4; ++j) {
                const int r = rbase + m * 16 + j;
                if (r < N) C[(size_t)r * M + cbase + n * 16] = f2bf(acc[m][n][j]);
            }
}

// ---------------------------------------------------------------------------
// CSR construction: zero -> histogram -> 2-level exclusive scan -> scatter
// ---------------------------------------------------------------------------
__global__ __launch_bounds__(256) void zero_kernel(int* __restrict__ p, int n) {
    const int i = blockIdx.x * 256 + threadIdx.x;
    if (i < n) p[i] = 0;
}

__global__ __launch_bounds__(256) void hist_kernel(const int* __restrict__ rows,
                                                   int* __restrict__ deg) {
    const int e = blockIdx.x * 256 + threadIdx.x;
    atomicAdd(&deg[rows[e]], 1);
}

__global__ __launch_bounds__(256) void sum_blocks_kernel(const int* __restrict__ deg,
                                                         int* __restrict__ bsum) {
    __shared__ int red[256];
    const int tid = threadIdx.x;
    const int i4  = blockIdx.x * 1024 + tid * 4;
    int s = 0;
#pragma unroll
    for (int k = 0; k < 4; ++k) {
        const int i = i4 + k;
        if (i < N_NODES) s += deg[i];
    }
    red[tid] = s;
    __syncthreads();
#pragma unroll
    for (int off = 128; off > 0; off >>= 1) {
        if (tid < off) red[tid] += red[tid + off];
        __syncthreads();
    }
    if (tid == 0) bsum[blockIdx.x] = red[0];
}

__global__ __launch_bounds__(256) void scan_bsum_kernel(const int* __restrict__ bsum,
                                                        int* __restrict__ boffs, int nblk) {
    __shared__ int sh[256];
    const int tid = threadIdx.x;
    sh[tid] = (tid < nblk) ? bsum[tid] : 0;
    __syncthreads();
    if (tid == 0) {
        int acc = 0;
        for (int b = 0; b < nblk; ++b) { const int t = sh[b]; sh[b] = acc; acc += t; }
    }
    __syncthreads();
    if (tid < nblk) boffs[tid] = sh[tid];
}

__global__ __launch_bounds__(256) void scan_final_kernel(const int* __restrict__ deg,
                                                         const int* __restrict__ boffs,
                                                         int* __restrict__ row_ptr,
                                                         int* __restrict__ cursor) {
    __shared__ int tsum[256];
    const int tid    = threadIdx.x;
    const int base_i = blockIdx.x * 1024 + tid * 4;
    int d[4];
#pragma unroll
    for (int k = 0; k < 4; ++k) {
        const int i = base_i + k;
        d[k] = (i < N_NODES) ? deg[i] : 0;
    }
    const int s = d[0] + d[1] + d[2] + d[3];
    tsum[tid] = s;
    __syncthreads();
    for (int off = 1; off < 256; off <<= 1) {
        const int t = (tid >= off) ? tsum[tid - off] : 0;
        __syncthreads();
        tsum[tid] += t;
        __syncthreads();
    }
    int p = tsum[tid] - s + boffs[blockIdx.x];
#pragma unroll
    for (int k = 0; k < 4; ++k) {
        const int i = base_i + k;
        if (i < N_NODES) {
            row_ptr[i] = p;
            cursor[i]  = p;
            if (i == N_NODES - 1) row_ptr[N_NODES] = p + d[k];
        }
        p += d[k];
    }
}

__global__ __launch_bounds__(256) void scatter_kernel(const int* __restrict__ rows,
                                                      const int* __restrict__ cols,
                                                      const float* __restrict__ vals,
                                                      int* __restrict__ cursor,
                                                      int* __restrict__ edge_col,
                                                      float* __restrict__ edge_val) {
    const int e = blockIdx.x * 256 + threadIdx.x;
    const int r = rows[e];
    const int pos = atomicAdd(&cursor[r], 1);
    edge_col[pos] = cols[e];
    edge_val[pos] = vals[e];
}

// ---------------------------------------------------------------------------
// Atomic-free SpMM over bf16 support table: one wave per output row.
// agg[r][:] = bias[:] + sum_{j in row r} val_j * sup[col_j][:]   (fp32 accum/out)
// ---------------------------------------------------------------------------
template<int DIM>  // 128 (bf16x2/lane) or 64 (bf16/lane)
__global__ __launch_bounds__(256) void spmm_kernel(const int* __restrict__ row_ptr,
                                                   const int* __restrict__ edge_col,
                                                   const float* __restrict__ edge_val,
                                                   const unsigned short* __restrict__ sup,
                                                   const float* __restrict__ bias,
                                                   float* __restrict__ agg) {
    const int wid  = (blockIdx.x * 256 + threadIdx.x) >> 6;  // row id
    const int lane = threadIdx.x & 63;
    if (wid >= N_NODES) return;

    const int start = row_ptr[wid];
    const int end   = row_ptr[wid + 1];

    float ax = 0.f, ay = 0.f;

    for (int j0 = start; j0 < end; j0 += 64) {
        int   c = 0;
        float v = 0.f;
        const int j = j0 + lane;
        if (j < end) { c = edge_col[j]; v = edge_val[j]; }
        const int cnt = min(64, end - j0);
        for (int k = 0; k < cnt; ++k) {
            const int   bc = __shfl(c, k);
            const float bv = __shfl(v, k);
            if (DIM == 128) {
                const unsigned int s =
                    *reinterpret_cast<const unsigned int*>(sup + (size_t)bc * 128 + lane * 2);
                ax = fmaf(bv, bfbits2f(s << 16), ax);
                ay = fmaf(bv, bfbits2f(s & 0xFFFF0000u), ay);
            } else {
                const unsigned int s = sup[(size_t)bc * 64 + lane];
                ax = fmaf(bv, bfbits2f(s << 16), ax);
            }
        }
    }

    if (DIM == 128) {
        float* dst = agg + (size_t)wid * 128 + lane * 2;
        dst[0] = ax + bias[lane * 2];
        dst[1] = ay + bias[lane * 2 + 1];
    } else {
        agg[(size_t)wid * 64 + lane] = ax + bias[lane];
    }
}

// ---------------------------------------------------------------------------
extern "C" void kernel_launch(void* const* d_in, const int* in_sizes, int n_in,
                              void* d_out, int out_size, void* d_ws, size_t ws_size,
                              hipStream_t stream) {
    const float* x    = (const float*)d_in[0];
    const int*   rows = (const int*)d_in[1];
    const int*   cols = (const int*)d_in[2];
    const float* vals = (const float*)d_in[3];
    const float* W0   = (const float*)d_in[4];
    const float* b0   = (const float*)d_in[5];
    const float* W1   = (const float*)d_in[6];
    const float* b1   = (const float*)d_in[7];
    float*       out  = (float*)d_out;

    // Workspace carve
    char* p = (char*)d_ws;
    unsigned short* sup0 = (unsigned short*)p;  p += (size_t)N_NODES * 128 * 2;  // 25.6 MB
    float*          h    = (float*)p;           p += (size_t)N_NODES * 128 * 4;  // 51.2 MB
    unsigned short* sup1 = (unsigned short*)p;  p += (size_t)N_NODES * 64 * 2;   // 12.8 MB
    unsigned short* W0t  = (unsigned short*)p;  p += (size_t)512 * 128 * 2;
    unsigned short* W1t  = (unsigned short*)p;  p += (size_t)128 * 64 * 2;
    int*   deg      = (int*)p;                  p += (size_t)N_NODES * 4;
    int*   row_ptr  = (int*)p;                  p += (size_t)(N_NODES + 4) * 4;
    int*   cursor   = (int*)p;                  p += (size_t)N_NODES * 4;
    int*   bsum     = (int*)p;                  p += 256 * 4;
    int*   boffs    = (int*)p;                  p += 256 * 4;
    int*   edge_col = (int*)p;                  p += (size_t)N_EDGES * 4;
    float* edge_val = (float*)p;                p += (size_t)N_EDGES * 4;

    constexpr int SCAN_BLOCKS = (N_NODES + 1023) / 1024;  // 98
    const int edge_blocks = N_EDGES / 256;
    const int node_blocks = (N_NODES + 255) / 256;
    const int gemm_blocks = (N_NODES + 127) / 128;        // 782
    const int spmm_blocks = (N_NODES * 64 + 255) / 256;   // 25000

    // ---- weight transpose/convert (tiny) ----
    convert_w_kernel<512, 128><<<(512 * 128 + 255) / 256, 256, 0, stream>>>(W0, W0t);
    convert_w_kernel<128, 64><<<(128 * 64 + 255) / 256, 256, 0, stream>>>(W1, W1t);

    // ---- CSR build (shared by both layers) ----
    zero_kernel<<<node_blocks, 256, 0, stream>>>(deg, N_NODES);
    hist_kernel<<<edge_blocks, 256, 0, stream>>>(rows, deg);
    sum_blocks_kernel<<<SCAN_BLOCKS, 256, 0, stream>>>(deg, bsum);
    scan_bsum_kernel<<<1, 256, 0, stream>>>(bsum, boffs, SCAN_BLOCKS);
    scan_final_kernel<<<SCAN_BLOCKS, 256, 0, stream>>>(deg, boffs, row_ptr, cursor);
    scatter_kernel<<<edge_blocks, 256, 0, stream>>>(rows, cols, vals, cursor, edge_col, edge_val);

    // ---- Layer 0 ----
    mfma_gemm_kernel<512, 128, false><<<gemm_blocks, 256, 0, stream>>>(x, W0t, sup0, N_NODES);
    spmm_kernel<128><<<spmm_blocks, 256, 0, stream>>>(row_ptr, edge_col, edge_val, sup0, b0, h);

    // ---- Layer 1 ----
    mfma_gemm_kernel<128, 64, true><<<gemm_blocks, 256, 0, stream>>>(h, W1t, sup1, N_NODES);
    spmm_kernel<64><<<spmm_blocks, 256, 0, stream>>>(row_ptr, edge_col, edge_val, sup1, b1, out);
}

// Round 4
// 436.662 us; speedup vs baseline: 4.3261x; 1.1614x over previous
//
#include <hip/hip_runtime.h>

#define N_NODES 100000
#define N_EDGES 1600000
// IN_DIM=512, HID_DIM=128, OUT_DIM=64

typedef __attribute__((ext_vector_type(8))) short bf16x8;
typedef __attribute__((ext_vector_type(4))) float f32x4;

__device__ __forceinline__ unsigned short f2bf(float f) {
    unsigned int u = __builtin_bit_cast(unsigned int, f);
    u = (u + 0x7FFFu + ((u >> 16) & 1u)) >> 16;   // RNE
    return (unsigned short)u;
}
__device__ __forceinline__ float bfu2f(unsigned short u) {
    return __builtin_bit_cast(float, (unsigned int)u << 16);
}

// Raw barrier: does NOT drain vmcnt, so global prefetch loads stay in flight.
__device__ __forceinline__ void block_barrier() {
    asm volatile("s_waitcnt lgkmcnt(0)" ::: "memory");
    __builtin_amdgcn_sched_barrier(0);
    __builtin_amdgcn_s_barrier();
    __builtin_amdgcn_sched_barrier(0);
}

// ---------------------------------------------------------------------------
// W[K][M] fp32 (row-major) -> Wt[M][K] bf16 (transposed)
// ---------------------------------------------------------------------------
template<int K, int M>
__global__ __launch_bounds__(256) void convert_w_kernel(const float* __restrict__ W,
                                                        unsigned short* __restrict__ Wt) {
    const int i = blockIdx.x * 256 + threadIdx.x;
    if (i < K * M) {
        const int k = i / M, c = i % M;
        Wt[c * K + k] = f2bf(W[i]);
    }
}

// ---------------------------------------------------------------------------
// Pipelined MFMA GEMM: C_bf16[N,M] = op(A_f32)[N,K] @ W, W as Wt[M][K] bf16.
// 256 thr = 4 waves (2m x 2n), tile 64 x M, BK=32. Prefetch depth 2 in regs
// (issue-early/write-late), double-buffered LDS, raw barriers (loads cross).
// LDS row stride 40 ushorts (80 B) -> <=2-way bank aliasing (free).
// ---------------------------------------------------------------------------
template<int K, int M, bool RELU>
__global__ __launch_bounds__(256) void mfma_gemm_kernel(const float* __restrict__ A,
                                                        const unsigned short* __restrict__ Wt,
                                                        unsigned short* __restrict__ C, int N) {
    constexpr int NSTEP = K / 32;   // k-steps
    constexpr int NFR   = M / 32;   // n-fragments per wave (4 for M=128, 2 for M=64)
    constexpr int NB    = M / 64;   // B uint4 loads per thread per step
    constexpr int LDT   = 40;       // LDS row stride (ushorts)

    __shared__ __align__(16) unsigned short As[2][64 * LDT];
    __shared__ __align__(16) unsigned short Bs[2][M * LDT];

    const int tid  = threadIdx.x;
    const int lane = tid & 63;
    const int wid  = tid >> 6;
    const int wm   = wid >> 1;
    const int wn   = wid & 1;
    const int brow = blockIdx.x * 64;

    float4 rA[2][2];
    uint4  rB[2][NB];

    // issue global loads for k-step t into reg slot (t&1)
    auto issue = [&](int t, int slot) {
        const int k0 = t * 32;
#pragma unroll
        for (int i = 0; i < 2; ++i) {
            const int id = tid + i * 256;
            const int r  = id >> 3;     // 0..63
            const int q  = id & 7;      // float4 index within 32-k row
            const int gr = brow + r;
            rA[slot][i] = (gr < N)
                ? *reinterpret_cast<const float4*>(A + (size_t)gr * K + k0 + q * 4)
                : make_float4(0.f, 0.f, 0.f, 0.f);
        }
#pragma unroll
        for (int i = 0; i < NB; ++i) {
            const int id = tid + i * 256;
            const int r  = id >> 2;     // 0..M-1
            const int q  = id & 3;      // 16B chunk within 32-k row
            rB[slot][i] = *reinterpret_cast<const uint4*>(Wt + (size_t)r * K + k0 + q * 8);
        }
    };

    // convert + write reg slot -> LDS buffer (same index)
    auto write_lds = [&](int slot) {
#pragma unroll
        for (int i = 0; i < 2; ++i) {
            const int id = tid + i * 256;
            const int r  = id >> 3;
            const int q  = id & 7;
            float4 v = rA[slot][i];
            if (RELU) {
                v.x = fmaxf(v.x, 0.f); v.y = fmaxf(v.y, 0.f);
                v.z = fmaxf(v.z, 0.f); v.w = fmaxf(v.w, 0.f);
            }
            uint2 pk;
            pk.x = (unsigned int)f2bf(v.x) | ((unsigned int)f2bf(v.y) << 16);
            pk.y = (unsigned int)f2bf(v.z) | ((unsigned int)f2bf(v.w) << 16);
            *reinterpret_cast<uint2*>(&As[slot][r * LDT + q * 4]) = pk;
        }
#pragma unroll
        for (int i = 0; i < NB; ++i) {
            const int id = tid + i * 256;
            const int r  = id >> 2;
            const int q  = id & 3;
            *reinterpret_cast<uint4*>(&Bs[slot][r * LDT + q * 8]) = rB[slot][i];
        }
    };

    f32x4 acc[2][NFR];
#pragma unroll
    for (int m = 0; m < 2; ++m)
#pragma unroll
        for (int n = 0; n < NFR; ++n) acc[m][n] = (f32x4){0.f, 0.f, 0.f, 0.f};

    const int afo = (wm * 32 + (lane & 15)) * LDT + (lane >> 4) * 8;
    const int bfo = (wn * (M / 2) + (lane & 15)) * LDT + (lane >> 4) * 8;

    // prologue: tiles 0,1 in flight; tile 0 -> LDS0
    issue(0, 0);
    issue(1, 1);
    write_lds(0);            // compiler inserts counted vmcnt wait for slot-0 regs
    block_barrier();

#pragma unroll
    for (int s = 0; s < NSTEP; ++s) {
        // fragments from LDS[s&1]
        bf16x8 af[2], bfr[NFR];
#pragma unroll
        for (int m = 0; m < 2; ++m)
            af[m] = *reinterpret_cast<const bf16x8*>(&As[s & 1][afo + m * 16 * LDT]);
#pragma unroll
        for (int n = 0; n < NFR; ++n)
            bfr[n] = *reinterpret_cast<const bf16x8*>(&Bs[s & 1][bfo + n * 16 * LDT]);

        if (s + 2 < NSTEP) issue(s + 2, s & 1);   // slot (s+2)&1 == s&1 (freed last iter)

#pragma unroll
        for (int m = 0; m < 2; ++m)
#pragma unroll
            for (int n = 0; n < NFR; ++n)
                acc[m][n] = __builtin_amdgcn_mfma_f32_16x16x32_bf16(af[m], bfr[n], acc[m][n], 0, 0, 0);

        if (s + 1 < NSTEP) write_lds((s + 1) & 1);  // waits (counted) on slot regs
        block_barrier();
    }

    // epilogue: C/D layout col=lane&15, row=(lane>>4)*4+j
    const int rb = brow + wm * 32 + (lane >> 4) * 4;
    const int cb = wn * (M / 2) + (lane & 15);
#pragma unroll
    for (int m = 0; m < 2; ++m)
#pragma unroll
        for (int n = 0; n < NFR; ++n)
#pragma unroll
            for (int j = 0; j < 4; ++j) {
                const int r = rb + m * 16 + j;
                if (r < N) C[(size_t)r * M + cb + n * 16] = f2bf(acc[m][n][j]);
            }
}

// ---------------------------------------------------------------------------
// CSR construction: zero -> histogram -> 2-level exclusive scan -> scatter
// ---------------------------------------------------------------------------
__global__ __launch_bounds__(256) void zero_kernel(int* __restrict__ p, int n) {
    const int i = blockIdx.x * 256 + threadIdx.x;
    if (i < n) p[i] = 0;
}

__global__ __launch_bounds__(256) void hist_kernel(const int* __restrict__ rows,
                                                   int* __restrict__ deg) {
    const int e = blockIdx.x * 256 + threadIdx.x;
    atomicAdd(&deg[rows[e]], 1);
}

__global__ __launch_bounds__(256) void sum_blocks_kernel(const int* __restrict__ deg,
                                                         int* __restrict__ bsum) {
    __shared__ int red[256];
    const int tid = threadIdx.x;
    const int i4  = blockIdx.x * 1024 + tid * 4;
    int s = 0;
#pragma unroll
    for (int k = 0; k < 4; ++k) {
        const int i = i4 + k;
        if (i < N_NODES) s += deg[i];
    }
    red[tid] = s;
    __syncthreads();
#pragma unroll
    for (int off = 128; off > 0; off >>= 1) {
        if (tid < off) red[tid] += red[tid + off];
        __syncthreads();
    }
    if (tid == 0) bsum[blockIdx.x] = red[0];
}

__global__ __launch_bounds__(256) void scan_bsum_kernel(const int* __restrict__ bsum,
                                                        int* __restrict__ boffs, int nblk) {
    __shared__ int sh[256];
    const int tid = threadIdx.x;
    sh[tid] = (tid < nblk) ? bsum[tid] : 0;
    __syncthreads();
    if (tid == 0) {
        int acc = 0;
        for (int b = 0; b < nblk; ++b) { const int t = sh[b]; sh[b] = acc; acc += t; }
    }
    __syncthreads();
    if (tid < nblk) boffs[tid] = sh[tid];
}

__global__ __launch_bounds__(256) void scan_final_kernel(const int* __restrict__ deg,
                                                         const int* __restrict__ boffs,
                                                         int* __restrict__ row_ptr,
                                                         int* __restrict__ cursor) {
    __shared__ int tsum[256];
    const int tid    = threadIdx.x;
    const int base_i = blockIdx.x * 1024 + tid * 4;
    int d[4];
#pragma unroll
    for (int k = 0; k < 4; ++k) {
        const int i = base_i + k;
        d[k] = (i < N_NODES) ? deg[i] : 0;
    }
    const int s = d[0] + d[1] + d[2] + d[3];
    tsum[tid] = s;
    __syncthreads();
    for (int off = 1; off < 256; off <<= 1) {
        const int t = (tid >= off) ? tsum[tid - off] : 0;
        __syncthreads();
        tsum[tid] += t;
        __syncthreads();
    }
    int p = tsum[tid] - s + boffs[blockIdx.x];
#pragma unroll
    for (int k = 0; k < 4; ++k) {
        const int i = base_i + k;
        if (i < N_NODES) {
            row_ptr[i] = p;
            cursor[i]  = p;
            if (i == N_NODES - 1) row_ptr[N_NODES] = p + d[k];
        }
        p += d[k];
    }
}

__global__ __launch_bounds__(256) void scatter_kernel(const int* __restrict__ rows,
                                                      const int* __restrict__ cols,
                                                      const float* __restrict__ vals,
                                                      int* __restrict__ cursor,
                                                      int* __restrict__ edge_col,
                                                      float* __restrict__ edge_val) {
    const int e = blockIdx.x * 256 + threadIdx.x;
    const int r = rows[e];
    const int pos = atomicAdd(&cursor[r], 1);
    edge_col[pos] = cols[e];
    edge_val[pos] = vals[e];
}

// ---------------------------------------------------------------------------
// Atomic-free SpMM over bf16 support table: one wave per output row, with
// edge-level MLP: NG sub-groups each gather a different edge's row slice.
// agg[r][:] = bias[:] + sum_j val_j * sup[col_j][:]   (fp32 accum/out)
// ---------------------------------------------------------------------------
template<int DIM>  // 128: 4 grp x 16 lanes; 64: 8 grp x 8 lanes (16B/lane both)
__global__ __launch_bounds__(256) void spmm_kernel(const int* __restrict__ row_ptr,
                                                   const int* __restrict__ edge_col,
                                                   const float* __restrict__ edge_val,
                                                   const unsigned short* __restrict__ sup,
                                                   const float* __restrict__ bias,
                                                   float* __restrict__ agg) {
    const int wv = (blockIdx.x * 256 + threadIdx.x) >> 6;  // row id
    if (wv >= N_NODES) return;
    const int lane = threadIdx.x & 63;

    constexpr int GL = DIM / 8;     // lanes per group (16 / 8)
    constexpr int NG = 64 / GL;     // edge-parallel groups (4 / 8)
    const int grp = lane / GL;
    const int sub = lane % GL;

    const int start = row_ptr[wv];
    const int end   = row_ptr[wv + 1];

    float a[8] = {0.f, 0.f, 0.f, 0.f, 0.f, 0.f, 0.f, 0.f};

    for (int j = start + grp; j < end; j += NG) {
        const int   c = edge_col[j];    // uniform within group -> broadcast
        const float v = edge_val[j];
        const bf16x8 s = *reinterpret_cast<const bf16x8*>(sup + (size_t)c * DIM + sub * 8);
#pragma unroll
        for (int d = 0; d < 8; ++d)
            a[d] = fmaf(v, bfu2f((unsigned short)s[d]), a[d]);
    }

    // cross-group reduction (lanes with equal `sub` hold the same dims)
#pragma unroll
    for (int d = 0; d < 8; ++d) {
        if (DIM == 64) a[d] += __shfl_xor(a[d], 8);
        a[d] += __shfl_xor(a[d], 16);
        a[d] += __shfl_xor(a[d], 32);
    }

    if (lane < GL) {
        float* dst = agg + (size_t)wv * DIM + sub * 8;
        const float4 b0 = *reinterpret_cast<const float4*>(bias + sub * 8);
        const float4 b1 = *reinterpret_cast<const float4*>(bias + sub * 8 + 4);
        *reinterpret_cast<float4*>(dst)     = make_float4(a[0] + b0.x, a[1] + b0.y, a[2] + b0.z, a[3] + b0.w);
        *reinterpret_cast<float4*>(dst + 4) = make_float4(a[4] + b1.x, a[5] + b1.y, a[6] + b1.z, a[7] + b1.w);
    }
}

// ---------------------------------------------------------------------------
extern "C" void kernel_launch(void* const* d_in, const int* in_sizes, int n_in,
                              void* d_out, int out_size, void* d_ws, size_t ws_size,
                              hipStream_t stream) {
    const float* x    = (const float*)d_in[0];
    const int*   rows = (const int*)d_in[1];
    const int*   cols = (const int*)d_in[2];
    const float* vals = (const float*)d_in[3];
    const float* W0   = (const float*)d_in[4];
    const float* b0   = (const float*)d_in[5];
    const float* W1   = (const float*)d_in[6];
    const float* b1   = (const float*)d_in[7];
    float*       out  = (float*)d_out;

    // Workspace carve
    char* p = (char*)d_ws;
    unsigned short* sup0 = (unsigned short*)p;  p += (size_t)N_NODES * 128 * 2;  // 25.6 MB
    float*          h    = (float*)p;           p += (size_t)N_NODES * 128 * 4;  // 51.2 MB
    unsigned short* sup1 = (unsigned short*)p;  p += (size_t)N_NODES * 64 * 2;   // 12.8 MB
    unsigned short* W0t  = (unsigned short*)p;  p += (size_t)512 * 128 * 2;
    unsigned short* W1t  = (unsigned short*)p;  p += (size_t)128 * 64 * 2;
    int*   deg      = (int*)p;                  p += (size_t)N_NODES * 4;
    int*   row_ptr  = (int*)p;                  p += (size_t)(N_NODES + 4) * 4;
    int*   cursor   = (int*)p;                  p += (size_t)N_NODES * 4;
    int*   bsum     = (int*)p;                  p += 256 * 4;
    int*   boffs    = (int*)p;                  p += 256 * 4;
    int*   edge_col = (int*)p;                  p += (size_t)N_EDGES * 4;
    float* edge_val = (float*)p;                p += (size_t)N_EDGES * 4;

    constexpr int SCAN_BLOCKS = (N_NODES + 1023) / 1024;  // 98
    const int edge_blocks = N_EDGES / 256;                // 6250
    const int node_blocks = (N_NODES + 255) / 256;
    const int gemm_blocks = (N_NODES + 63) / 64;          // 1563
    const int spmm_blocks = (N_NODES * 64 + 255) / 256;   // 25000

    // ---- weight transpose/convert (tiny) ----
    convert_w_kernel<512, 128><<<(512 * 128 + 255) / 256, 256, 0, stream>>>(W0, W0t);
    convert_w_kernel<128, 64><<<(128 * 64 + 255) / 256, 256, 0, stream>>>(W1, W1t);

    // ---- CSR build (shared by both layers) ----
    zero_kernel<<<node_blocks, 256, 0, stream>>>(deg, N_NODES);
    hist_kernel<<<edge_blocks, 256, 0, stream>>>(rows, deg);
    sum_blocks_kernel<<<SCAN_BLOCKS, 256, 0, stream>>>(deg, bsum);
    scan_bsum_kernel<<<1, 256, 0, stream>>>(bsum, boffs, SCAN_BLOCKS);
    scan_final_kernel<<<SCAN_BLOCKS, 256, 0, stream>>>(deg, boffs, row_ptr, cursor);
    scatter_kernel<<<edge_blocks, 256, 0, stream>>>(rows, cols, vals, cursor, edge_col, edge_val);

    // ---- Layer 0 ----
    mfma_gemm_kernel<512, 128, false><<<gemm_blocks, 256, 0, stream>>>(x, W0t, sup0, N_NODES);
    spmm_kernel<128><<<spmm_blocks, 256, 0, stream>>>(row_ptr, edge_col, edge_val, sup0, b0, h);

    // ---- Layer 1 ----
    mfma_gemm_kernel<128, 64, true><<<gemm_blocks, 256, 0, stream>>>(h, W1t, sup1, N_NODES);
    spmm_kernel<64><<<spmm_blocks, 256, 0, stream>>>(row_ptr, edge_col, edge_val, sup1, b1, out);
}

// Round 5
// 374.775 us; speedup vs baseline: 5.0405x; 1.1651x over previous
//
#include <hip/hip_runtime.h>

#define N_NODES 100000
#define N_EDGES 1600000
// IN_DIM=512, HID_DIM=128, OUT_DIM=64

typedef __attribute__((ext_vector_type(8))) short bf16x8;
typedef __attribute__((ext_vector_type(4))) float f32x4;

__device__ __forceinline__ unsigned short f2bf(float f) {
    unsigned int u = __builtin_bit_cast(unsigned int, f);
    u = (u + 0x7FFFu + ((u >> 16) & 1u)) >> 16;   // RNE
    return (unsigned short)u;
}
__device__ __forceinline__ float bfu2f(unsigned short u) {
    return __builtin_bit_cast(float, (unsigned int)u << 16);
}

// Raw barrier: waits LDS ops only — global prefetch loads stay in flight.
__device__ __forceinline__ void block_barrier() {
    asm volatile("s_waitcnt lgkmcnt(0)" ::: "memory");
    __builtin_amdgcn_sched_barrier(0);
    __builtin_amdgcn_s_barrier();
    __builtin_amdgcn_sched_barrier(0);
}

// ---------------------------------------------------------------------------
// W[K][M] fp32 (row-major) -> Wt[M][K] bf16 (transposed)
// ---------------------------------------------------------------------------
template<int K, int M>
__global__ __launch_bounds__(256) void convert_w_kernel(const float* __restrict__ W,
                                                        unsigned short* __restrict__ Wt) {
    const int i = blockIdx.x * 256 + threadIdx.x;
    if (i < K * M) {
        const int k = i / M, c = i % M;
        Wt[c * K + k] = f2bf(W[i]);
    }
}

// ---------------------------------------------------------------------------
// Pipelined MFMA GEMM: C_bf16[N,M] = op(A_f32)[N,K] @ W, W as Wt[M][K] bf16.
// 256 thr = 4 waves (2m x 2n), tile 64 x M, BK=32. Depth-2 prefetch held in
// NAMED registers (rule #20: no runtime-indexed register arrays -> no scratch).
// Double-buffered LDS, raw barriers (prefetch loads cross barriers).
// LDS row stride 40 ushorts (80 B) -> <=2-way bank aliasing on fragment reads.
// ---------------------------------------------------------------------------
template<int K, int M, bool RELU>
__global__ __launch_bounds__(256) void mfma_gemm_kernel(const float* __restrict__ A,
                                                        const unsigned short* __restrict__ Wt,
                                                        unsigned short* __restrict__ C, int N) {
    constexpr int NSTEP = K / 32;   // k-steps (16 / 4)
    constexpr int NFR   = M / 32;   // n-fragments per wave (4 / 2)
    constexpr int NB    = M / 64;   // B uint4 loads per thread per step (2 / 1)
    constexpr int LDT   = 40;       // LDS row stride (ushorts)

    __shared__ __align__(16) unsigned short As[2][64 * LDT];
    __shared__ __align__(16) unsigned short Bs[2][M * LDT];

    const int tid  = threadIdx.x;
    const int lane = tid & 63;
    const int wid  = tid >> 6;
    const int wm   = wid >> 1;
    const int wn   = wid & 1;
    const int brow = blockIdx.x * 64;

    // staging coordinates (fixed per thread)
    const int ar0 = tid >> 3, akq = tid & 7;          // A: rows 0..31 / chunk
    const int ar1 = ar0 + 32;                         //    rows 32..63
    const bool v0 = (brow + ar0) < N;
    const bool v1 = (brow + ar1) < N;
    const float* ap0 = A + (size_t)(brow + ar0) * K + akq * 4;
    const float* ap1 = A + (size_t)(brow + ar1) * K + akq * 4;
    const int br0 = tid >> 2, bkq = tid & 3;          // B: rows 0..63 / 16B chunk
    const unsigned short* bp0 = Wt + (size_t)br0 * K + bkq * 8;
    const unsigned short* bp1 = Wt + (size_t)(br0 + 64) * K + bkq * 8;  // NB==2 only

    // ---- depth-2 prefetch slots: NAMED registers ----
    float4 A0a, A0b, A1a, A1b;
    uint4  B0a, B0b, B1a, B1b;

    auto issue0 = [&](int t) {
        const int ko = t * 32;
        A0a = v0 ? *reinterpret_cast<const float4*>(ap0 + ko) : make_float4(0.f, 0.f, 0.f, 0.f);
        A0b = v1 ? *reinterpret_cast<const float4*>(ap1 + ko) : make_float4(0.f, 0.f, 0.f, 0.f);
        B0a = *reinterpret_cast<const uint4*>(bp0 + ko);
        if (NB == 2) B0b = *reinterpret_cast<const uint4*>(bp1 + ko);
    };
    auto issue1 = [&](int t) {
        const int ko = t * 32;
        A1a = v0 ? *reinterpret_cast<const float4*>(ap0 + ko) : make_float4(0.f, 0.f, 0.f, 0.f);
        A1b = v1 ? *reinterpret_cast<const float4*>(ap1 + ko) : make_float4(0.f, 0.f, 0.f, 0.f);
        B1a = *reinterpret_cast<const uint4*>(bp0 + ko);
        if (NB == 2) B1b = *reinterpret_cast<const uint4*>(bp1 + ko);
    };

    auto pack = [&](float4 v) -> uint2 {
        if (RELU) {
            v.x = fmaxf(v.x, 0.f); v.y = fmaxf(v.y, 0.f);
            v.z = fmaxf(v.z, 0.f); v.w = fmaxf(v.w, 0.f);
        }
        uint2 p;
        p.x = (unsigned int)f2bf(v.x) | ((unsigned int)f2bf(v.y) << 16);
        p.y = (unsigned int)f2bf(v.z) | ((unsigned int)f2bf(v.w) << 16);
        return p;
    };
    auto wlds0 = [&](int buf) {   // slot0 regs -> LDS[buf]
        *reinterpret_cast<uint2*>(&As[buf][ar0 * LDT + akq * 4]) = pack(A0a);
        *reinterpret_cast<uint2*>(&As[buf][ar1 * LDT + akq * 4]) = pack(A0b);
        *reinterpret_cast<uint4*>(&Bs[buf][br0 * LDT + bkq * 8]) = B0a;
        if (NB == 2) *reinterpret_cast<uint4*>(&Bs[buf][(br0 + 64) * LDT + bkq * 8]) = B0b;
    };
    auto wlds1 = [&](int buf) {   // slot1 regs -> LDS[buf]
        *reinterpret_cast<uint2*>(&As[buf][ar0 * LDT + akq * 4]) = pack(A1a);
        *reinterpret_cast<uint2*>(&As[buf][ar1 * LDT + akq * 4]) = pack(A1b);
        *reinterpret_cast<uint4*>(&Bs[buf][br0 * LDT + bkq * 8]) = B1a;
        if (NB == 2) *reinterpret_cast<uint4*>(&Bs[buf][(br0 + 64) * LDT + bkq * 8]) = B1b;
    };

    f32x4 acc[2][NFR];
#pragma unroll
    for (int m = 0; m < 2; ++m)
#pragma unroll
        for (int n = 0; n < NFR; ++n) acc[m][n] = (f32x4){0.f, 0.f, 0.f, 0.f};

    const int afo = (wm * 32 + (lane & 15)) * LDT + (lane >> 4) * 8;
    const int bfo = (wn * (M / 2) + (lane & 15)) * LDT + (lane >> 4) * 8;

    auto step = [&](int buf) {    // fragments from LDS[buf] + MFMA
        bf16x8 af[2], bfr[NFR];
#pragma unroll
        for (int m = 0; m < 2; ++m)
            af[m] = *reinterpret_cast<const bf16x8*>(&As[buf][afo + m * 16 * LDT]);
#pragma unroll
        for (int n = 0; n < NFR; ++n)
            bfr[n] = *reinterpret_cast<const bf16x8*>(&Bs[buf][bfo + n * 16 * LDT]);
#pragma unroll
        for (int m = 0; m < 2; ++m)
#pragma unroll
            for (int n = 0; n < NFR; ++n)
                acc[m][n] = __builtin_amdgcn_mfma_f32_16x16x32_bf16(af[m], bfr[n], acc[m][n], 0, 0, 0);
    };

    // prologue: steps 0,1 in flight; step 0 -> LDS0
    issue0(0);
    issue1(1);
    wlds0(0);                 // counted vmcnt wait on slot0 only
    block_barrier();

#pragma unroll
    for (int i = 0; i < NSTEP / 2; ++i) {
        const int t = 2 * i;
        // even step t: data in LDS0; slot0 free
        if (t + 2 < NSTEP) issue0(t + 2);
        step(0);
        wlds1(1);             // step t+1 data -> LDS1
        block_barrier();
        // odd step t+1: data in LDS1; slot1 free
        if (t + 3 < NSTEP) issue1(t + 3);
        step(1);
        if (t + 2 < NSTEP) wlds0(0);   // step t+2 data -> LDS0
        block_barrier();
    }

    // epilogue: C/D layout col=lane&15, row=(lane>>4)*4+j
    const int rb = brow + wm * 32 + (lane >> 4) * 4;
    const int cb = wn * (M / 2) + (lane & 15);
#pragma unroll
    for (int m = 0; m < 2; ++m)
#pragma unroll
        for (int n = 0; n < NFR; ++n)
#pragma unroll
            for (int j = 0; j < 4; ++j) {
                const int r = rb + m * 16 + j;
                if (r < N) C[(size_t)r * M + cb + n * 16] = f2bf(acc[m][n][j]);
            }
}

// ---------------------------------------------------------------------------
// CSR construction: zero -> histogram -> 2-level exclusive scan -> scatter
// ---------------------------------------------------------------------------
__global__ __launch_bounds__(256) void zero_kernel(int* __restrict__ p, int n) {
    const int i = blockIdx.x * 256 + threadIdx.x;
    if (i < n) p[i] = 0;
}

__global__ __launch_bounds__(256) void hist_kernel(const int* __restrict__ rows,
                                                   int* __restrict__ deg) {
    const int e = blockIdx.x * 256 + threadIdx.x;
    atomicAdd(&deg[rows[e]], 1);
}

__global__ __launch_bounds__(256) void sum_blocks_kernel(const int* __restrict__ deg,
                                                         int* __restrict__ bsum) {
    __shared__ int red[256];
    const int tid = threadIdx.x;
    const int i4  = blockIdx.x * 1024 + tid * 4;
    int s = 0;
#pragma unroll
    for (int k = 0; k < 4; ++k) {
        const int i = i4 + k;
        if (i < N_NODES) s += deg[i];
    }
    red[tid] = s;
    __syncthreads();
#pragma unroll
    for (int off = 128; off > 0; off >>= 1) {
        if (tid < off) red[tid] += red[tid + off];
        __syncthreads();
    }
    if (tid == 0) bsum[blockIdx.x] = red[0];
}

__global__ __launch_bounds__(256) void scan_bsum_kernel(const int* __restrict__ bsum,
                                                        int* __restrict__ boffs, int nblk) {
    __shared__ int sh[256];
    const int tid = threadIdx.x;
    sh[tid] = (tid < nblk) ? bsum[tid] : 0;
    __syncthreads();
    if (tid == 0) {
        int acc = 0;
        for (int b = 0; b < nblk; ++b) { const int t = sh[b]; sh[b] = acc; acc += t; }
    }
    __syncthreads();
    if (tid < nblk) boffs[tid] = sh[tid];
}

__global__ __launch_bounds__(256) void scan_final_kernel(const int* __restrict__ deg,
                                                         const int* __restrict__ boffs,
                                                         int* __restrict__ row_ptr,
                                                         int* __restrict__ cursor) {
    __shared__ int tsum[256];
    const int tid    = threadIdx.x;
    const int base_i = blockIdx.x * 1024 + tid * 4;
    int d[4];
#pragma unroll
    for (int k = 0; k < 4; ++k) {
        const int i = base_i + k;
        d[k] = (i < N_NODES) ? deg[i] : 0;
    }
    const int s = d[0] + d[1] + d[2] + d[3];
    tsum[tid] = s;
    __syncthreads();
    for (int off = 1; off < 256; off <<= 1) {
        const int t = (tid >= off) ? tsum[tid - off] : 0;
        __syncthreads();
        tsum[tid] += t;
        __syncthreads();
    }
    int p = tsum[tid] - s + boffs[blockIdx.x];
#pragma unroll
    for (int k = 0; k < 4; ++k) {
        const int i = base_i + k;
        if (i < N_NODES) {
            row_ptr[i] = p;
            cursor[i]  = p;
            if (i == N_NODES - 1) row_ptr[N_NODES] = p + d[k];
        }
        p += d[k];
    }
}

__global__ __launch_bounds__(256) void scatter_kernel(const int* __restrict__ rows,
                                                      const int* __restrict__ cols,
                                                      const float* __restrict__ vals,
                                                      int* __restrict__ cursor,
                                                      int* __restrict__ edge_col,
                                                      float* __restrict__ edge_val) {
    const int e = blockIdx.x * 256 + threadIdx.x;
    const int r = rows[e];
    const int pos = atomicAdd(&cursor[r], 1);
    edge_col[pos] = cols[e];
    edge_val[pos] = vals[e];
}

// ---------------------------------------------------------------------------
// Atomic-free SpMM over bf16 support table: one wave per output row, with
// edge-level MLP: NG sub-groups each gather a different edge's row slice.
// agg[r][:] = bias[:] + sum_j val_j * sup[col_j][:]   (fp32 accum/out)
// ---------------------------------------------------------------------------
template<int DIM>  // 128: 4 grp x 16 lanes; 64: 8 grp x 8 lanes (16B/lane both)
__global__ __launch_bounds__(256) void spmm_kernel(const int* __restrict__ row_ptr,
                                                   const int* __restrict__ edge_col,
                                                   const float* __restrict__ edge_val,
                                                   const unsigned short* __restrict__ sup,
                                                   const float* __restrict__ bias,
                                                   float* __restrict__ agg) {
    const int wv = (blockIdx.x * 256 + threadIdx.x) >> 6;  // row id
    if (wv >= N_NODES) return;
    const int lane = threadIdx.x & 63;

    constexpr int GL = DIM / 8;     // lanes per group (16 / 8)
    constexpr int NG = 64 / GL;     // edge-parallel groups (4 / 8)
    const int grp = lane / GL;
    const int sub = lane % GL;

    const int start = row_ptr[wv];
    const int end   = row_ptr[wv + 1];

    float a[8] = {0.f, 0.f, 0.f, 0.f, 0.f, 0.f, 0.f, 0.f};

    for (int j = start + grp; j < end; j += NG) {
        const int   c = edge_col[j];    // uniform within group -> broadcast
        const float v = edge_val[j];
        const bf16x8 s = *reinterpret_cast<const bf16x8*>(sup + (size_t)c * DIM + sub * 8);
#pragma unroll
        for (int d = 0; d < 8; ++d)
            a[d] = fmaf(v, bfu2f((unsigned short)s[d]), a[d]);
    }

    // cross-group reduction (lanes with equal `sub` hold the same dims)
#pragma unroll
    for (int d = 0; d < 8; ++d) {
        if (DIM == 64) a[d] += __shfl_xor(a[d], 8);
        a[d] += __shfl_xor(a[d], 16);
        a[d] += __shfl_xor(a[d], 32);
    }

    if (lane < GL) {
        float* dst = agg + (size_t)wv * DIM + sub * 8;
        const float4 b0 = *reinterpret_cast<const float4*>(bias + sub * 8);
        const float4 b1 = *reinterpret_cast<const float4*>(bias + sub * 8 + 4);
        *reinterpret_cast<float4*>(dst)     = make_float4(a[0] + b0.x, a[1] + b0.y, a[2] + b0.z, a[3] + b0.w);
        *reinterpret_cast<float4*>(dst + 4) = make_float4(a[4] + b1.x, a[5] + b1.y, a[6] + b1.z, a[7] + b1.w);
    }
}

// ---------------------------------------------------------------------------
extern "C" void kernel_launch(void* const* d_in, const int* in_sizes, int n_in,
                              void* d_out, int out_size, void* d_ws, size_t ws_size,
                              hipStream_t stream) {
    const float* x    = (const float*)d_in[0];
    const int*   rows = (const int*)d_in[1];
    const int*   cols = (const int*)d_in[2];
    const float* vals = (const float*)d_in[3];
    const float* W0   = (const float*)d_in[4];
    const float* b0   = (const float*)d_in[5];
    const float* W1   = (const float*)d_in[6];
    const float* b1   = (const float*)d_in[7];
    float*       out  = (float*)d_out;

    // Workspace carve
    char* p = (char*)d_ws;
    unsigned short* sup0 = (unsigned short*)p;  p += (size_t)N_NODES * 128 * 2;  // 25.6 MB
    float*          h    = (float*)p;           p += (size_t)N_NODES * 128 * 4;  // 51.2 MB
    unsigned short* sup1 = (unsigned short*)p;  p += (size_t)N_NODES * 64 * 2;   // 12.8 MB
    unsigned short* W0t  = (unsigned short*)p;  p += (size_t)512 * 128 * 2;
    unsigned short* W1t  = (unsigned short*)p;  p += (size_t)128 * 64 * 2;
    int*   deg      = (int*)p;                  p += (size_t)N_NODES * 4;
    int*   row_ptr  = (int*)p;                  p += (size_t)(N_NODES + 4) * 4;
    int*   cursor   = (int*)p;                  p += (size_t)N_NODES * 4;
    int*   bsum     = (int*)p;                  p += 256 * 4;
    int*   boffs    = (int*)p;                  p += 256 * 4;
    int*   edge_col = (int*)p;                  p += (size_t)N_EDGES * 4;
    float* edge_val = (float*)p;                p += (size_t)N_EDGES * 4;

    constexpr int SCAN_BLOCKS = (N_NODES + 1023) / 1024;  // 98
    const int edge_blocks = N_EDGES / 256;                // 6250
    const int node_blocks = (N_NODES + 255) / 256;
    const int gemm_blocks = (N_NODES + 63) / 64;          // 1563
    const int spmm_blocks = (N_NODES * 64 + 255) / 256;   // 25000

    // ---- weight transpose/convert (tiny) ----
    convert_w_kernel<512, 128><<<(512 * 128 + 255) / 256, 256, 0, stream>>>(W0, W0t);
    convert_w_kernel<128, 64><<<(128 * 64 + 255) / 256, 256, 0, stream>>>(W1, W1t);

    // ---- CSR build (shared by both layers) ----
    zero_kernel<<<node_blocks, 256, 0, stream>>>(deg, N_NODES);
    hist_kernel<<<edge_blocks, 256, 0, stream>>>(rows, deg);
    sum_blocks_kernel<<<SCAN_BLOCKS, 256, 0, stream>>>(deg, bsum);
    scan_bsum_kernel<<<1, 256, 0, stream>>>(bsum, boffs, SCAN_BLOCKS);
    scan_final_kernel<<<SCAN_BLOCKS, 256, 0, stream>>>(deg, boffs, row_ptr, cursor);
    scatter_kernel<<<edge_blocks, 256, 0, stream>>>(rows, cols, vals, cursor, edge_col, edge_val);

    // ---- Layer 0 ----
    mfma_gemm_kernel<512, 128, false><<<gemm_blocks, 256, 0, stream>>>(x, W0t, sup0, N_NODES);
    spmm_kernel<128><<<spmm_blocks, 256, 0, stream>>>(row_ptr, edge_col, edge_val, sup0, b0, h);

    // ---- Layer 1 ----
    mfma_gemm_kernel<128, 64, true><<<gemm_blocks, 256, 0, stream>>>(h, W1t, sup1, N_NODES);
    spmm_kernel<64><<<spmm_blocks, 256, 0, stream>>>(row_ptr, edge_col, edge_val, sup1, b1, out);
}